// Round 1
// baseline (336.090 us; speedup 1.0000x reference)
//
#include <hip/hip_runtime.h>

// WeightedEmbedding: out[b,s,d] = sum_v x[b,s,v] * W[v,d]
// = GEMM  M=B*S=8192, K=V=4096, N=D=32, fp32.
//
// Structure: LDS-free. Lane = (h = v-phase 0..7, d4 = d-quad 0..7).
// W chunk (64 v) held in registers phase-split across lanes (8 float4/lane);
// x read straight from global with 8-lane broadcast addresses (coalescer
// collapses them). Epilogue: shfl_xor butterfly over the 8 v-phase lanes.

constexpr int V  = 4096;   // vocab (K)
constexpr int D  = 32;     // embed dim (N)
constexpr int KV = 64;     // v per chunk
constexpr int WM = 8;      // rows per wave
constexpr int WAVES = 2;   // waves per block
constexpr int BM = WM * WAVES;  // 16 rows per block

#define FMA4(A, S, W4) \
  do { (A).x = fmaf((S), (W4).x, (A).x); \
       (A).y = fmaf((S), (W4).y, (A).y); \
       (A).z = fmaf((S), (W4).z, (A).z); \
       (A).w = fmaf((S), (W4).w, (A).w); } while (0)

__global__ __launch_bounds__(WAVES * 64, 2)
void WeightedEmbedding_48249662603573_kernel(const float* __restrict__ x,
                                             const float* __restrict__ w,
                                             float* __restrict__ out,
                                             int M) {
  const int tid  = threadIdx.x;
  const int wave = tid >> 6;
  const int lane = tid & 63;
  const int d4   = lane & 7;   // owns d = d4*4 .. d4*4+3
  const int h    = lane >> 3;  // v-phase: owns v = v0 + h*8 .. +7
  const int r0   = blockIdx.x * BM + wave * WM;  // wave's first row

  float4 acc[WM];
#pragma unroll
  for (int m = 0; m < WM; ++m) acc[m] = make_float4(0.f, 0.f, 0.f, 0.f);

  const float* wbase = w + (size_t)(h * 8) * D + d4 * 4;
  const float* xbase = x + (size_t)r0 * V + h * 8;

  for (int v0 = 0; v0 < V; v0 += KV) {
    // --- W chunk -> registers (phase-split): wr[j] = W[v0 + h*8 + j][d4*4 ..+3]
    float4 wr[8];
    const float* wp = wbase + (size_t)v0 * D;
#pragma unroll
    for (int j = 0; j < 8; ++j)
      wr[j] = *(const float4*)(wp + (size_t)j * D);

    // --- rows: x broadcast-loaded from global, 32 FMAs per row per lane
#pragma unroll
    for (int m = 0; m < WM; ++m) {
      const float* xp = xbase + (size_t)m * V + v0;
      float4 xa = *(const float4*)(xp);
      float4 xb = *(const float4*)(xp + 4);
      FMA4(acc[m], xa.x, wr[0]);
      FMA4(acc[m], xa.y, wr[1]);
      FMA4(acc[m], xa.z, wr[2]);
      FMA4(acc[m], xa.w, wr[3]);
      FMA4(acc[m], xb.x, wr[4]);
      FMA4(acc[m], xb.y, wr[5]);
      FMA4(acc[m], xb.z, wr[6]);
      FMA4(acc[m], xb.w, wr[7]);
    }
  }

  // --- reduce partial sums across the 8 v-phase lanes (lane bits 3..5)
#pragma unroll
  for (int off = 8; off <= 32; off <<= 1) {
#pragma unroll
    for (int m = 0; m < WM; ++m) {
      acc[m].x += __shfl_xor(acc[m].x, off, 64);
      acc[m].y += __shfl_xor(acc[m].y, off, 64);
      acc[m].z += __shfl_xor(acc[m].z, off, 64);
      acc[m].w += __shfl_xor(acc[m].w, off, 64);
    }
  }

  // lane (h, d4) stores row r0+h, cols d4*4..d4*4+3  (static-index pick, rule #20)
  float4 res = acc[0];
#pragma unroll
  for (int m = 1; m < WM; ++m)
    if (h == m) res = acc[m];

  const int row = r0 + h;
  if (row < M)
    *(float4*)(out + (size_t)row * D + d4 * 4) = res;
}

extern "C" void kernel_launch(void* const* d_in, const int* in_sizes, int n_in,
                              void* d_out, int out_size, void* d_ws, size_t ws_size,
                              hipStream_t stream) {
  const float* x = (const float*)d_in[0];
  const float* w = (const float*)d_in[1];
  float* out = (float*)d_out;

  const int M = in_sizes[0] / V;       // 8192
  dim3 grid((M + BM - 1) / BM);        // 512 blocks
  dim3 block(WAVES * 64);              // 128 threads
  hipLaunchKernelGGL(WeightedEmbedding_48249662603573_kernel,
                     grid, block, 0, stream, x, w, out, M);
}

// Round 3
// 228.586 us; speedup vs baseline: 1.4703x; 1.4703x over previous
//
#include <hip/hip_runtime.h>

// WeightedEmbedding: out[b,s,d] = sum_v x[b,s,v] * W[v,d]
// GEMM M=B*S=8192, K=V=4096, N=D=32, fp32.
//
// Structure: register-held W (no LDS staging for W), in-block K-split
// for 4x occupancy (4 waves/SIMD), explicit load-group hoisting for ILP.
// Block = 256 thr = 4 waves; all 4 waves own the SAME 8 rows, each wave a
// K-quarter (1024 v). Lane = (h = v-phase 0..7, d4 = d-quad 0..7).
// Final cross-wave reduce through 4 KB LDS; coalesced 1 KB store per block.

typedef float f32x4 __attribute__((ext_vector_type(4)));  // native vec: OK for nontemporal builtins

constexpr int V      = 4096;   // vocab (K)
constexpr int D      = 32;     // embed dim (N)
constexpr int KV     = 64;     // v per chunk
constexpr int WM     = 8;      // rows per block (shared by all waves)
constexpr int KWAVES = 4;      // K-split factor = waves per block
constexpr int KQ     = V / KWAVES;        // 1024 v per wave
constexpr int NCHUNK = KQ / KV;           // 16 chunks per wave

#define FMA4(A, S, W4) \
  do { (A).x = fmaf((S), (W4).x, (A).x); \
       (A).y = fmaf((S), (W4).y, (A).y); \
       (A).z = fmaf((S), (W4).z, (A).z); \
       (A).w = fmaf((S), (W4).w, (A).w); } while (0)

__global__ __launch_bounds__(KWAVES * 64, 4)
void WeightedEmbedding_48249662603573_kernel(const float* __restrict__ x,
                                             const float* __restrict__ w,
                                             float* __restrict__ out,
                                             int M) {
  const int tid  = threadIdx.x;
  const int kq   = tid >> 6;   // this wave's K-quarter
  const int lane = tid & 63;
  const int d4   = lane & 7;   // owns d = d4*4 .. d4*4+3
  const int h    = lane >> 3;  // v-phase: v = v0 + h*8 .. +7
  const int r0   = blockIdx.x * WM;

  f32x4 acc[WM];
#pragma unroll
  for (int m = 0; m < WM; ++m) acc[m] = (f32x4)(0.f);

  const int k0 = kq * KQ;
  const float* wbase = w + (size_t)(k0 + h * 8) * D + d4 * 4;
  const float* xbase = x + (size_t)r0 * V + k0 + h * 8;

  for (int c = 0; c < NCHUNK; ++c) {
    // --- W chunk -> registers (phase-split), all 8 loads issued up front
    f32x4 wr[8];
    const float* wp = wbase + (size_t)(c * KV) * D;
#pragma unroll
    for (int j = 0; j < 8; ++j)
      wr[j] = *(const f32x4*)(wp + (size_t)j * D);

    // --- rows in two groups of 4: issue 8 x-loads, then FMA the group.
    // Nontemporal: x streams once; keep it from evicting W in L2.
#pragma unroll
    for (int g = 0; g < 2; ++g) {
      f32x4 xa[4], xb[4];
#pragma unroll
      for (int mm = 0; mm < 4; ++mm) {
        const float* xp = xbase + (size_t)(g * 4 + mm) * V + c * KV;
        xa[mm] = __builtin_nontemporal_load((const f32x4*)xp);
        xb[mm] = __builtin_nontemporal_load((const f32x4*)xp + 1);
      }
#pragma unroll
      for (int mm = 0; mm < 4; ++mm) {
        const int m = g * 4 + mm;
        FMA4(acc[m], xa[mm].x, wr[0]);
        FMA4(acc[m], xa[mm].y, wr[1]);
        FMA4(acc[m], xa[mm].z, wr[2]);
        FMA4(acc[m], xa[mm].w, wr[3]);
        FMA4(acc[m], xb[mm].x, wr[4]);
        FMA4(acc[m], xb[mm].y, wr[5]);
        FMA4(acc[m], xb[mm].z, wr[6]);
        FMA4(acc[m], xb[mm].w, wr[7]);
      }
    }
  }

  // --- butterfly reduce across the 8 v-phase lanes (lane bits 3..5)
#pragma unroll
  for (int off = 8; off <= 32; off <<= 1) {
#pragma unroll
    for (int m = 0; m < WM; ++m) {
      acc[m].x += __shfl_xor(acc[m].x, off, 64);
      acc[m].y += __shfl_xor(acc[m].y, off, 64);
      acc[m].z += __shfl_xor(acc[m].z, off, 64);
      acc[m].w += __shfl_xor(acc[m].w, off, 64);
    }
  }

  // lane (h,d4) holds row h's partial for this K-quarter (static pick, rule #20)
  f32x4 res = acc[0];
#pragma unroll
  for (int m = 1; m < WM; ++m)
    if (h == m) res = acc[m];

  // --- cross-wave (K-quarter) reduce through LDS
  __shared__ f32x4 red[KWAVES][WM][8];   // 4 KB
  red[kq][h][d4] = res;
  __syncthreads();

  const int row = tid >> 5;        // 0..7
  const int d   = tid & 31;        // 0..31
  const float* rf = (const float*)red;
  const int idx = row * D + d;     // within one kq slice (256 floats)
  float s = rf[idx] + rf[256 + idx] + rf[512 + idx] + rf[768 + idx];
  if (r0 + row < M)
    out[(size_t)(r0 + row) * D + d] = s;
}

extern "C" void kernel_launch(void* const* d_in, const int* in_sizes, int n_in,
                              void* d_out, int out_size, void* d_ws, size_t ws_size,
                              hipStream_t stream) {
  const float* x = (const float*)d_in[0];
  const float* w = (const float*)d_in[1];
  float* out = (float*)d_out;

  const int M = in_sizes[0] / V;           // 8192
  dim3 grid((M + WM - 1) / WM);            // 1024 blocks
  dim3 block(KWAVES * 64);                 // 256 threads = 4 waves
  hipLaunchKernelGGL(WeightedEmbedding_48249662603573_kernel,
                     grid, block, 0, stream, x, w, out, M);
}

// Round 4
// 211.301 us; speedup vs baseline: 1.5906x; 1.0818x over previous
//
#include <hip/hip_runtime.h>

// WeightedEmbedding: out[b,s,d] = sum_v x[b,s,v] * W[v,d]
// GEMM M=B*S=8192, K=V=4096, N=D=32, fp32.
//
// Round-4: kill load serialization (r3: VGPR=60 forced ~24 serialized
// ~500cy latencies/chunk). x now staged via async global_load_lds (zero
// VGPR cost, 4-buffer ring, depth-2 prefetch, counted vmcnt(4) — never
// drained, no barriers in main loop; buffers are wave-private). W chunk in
// registers (8 independent L2-hot loads). Block = 4 waves sharing 8 rows,
// each wave a K-quarter; cross-wave reduce via 4KB LDS at the end.

typedef float f32x4 __attribute__((ext_vector_type(4)));

constexpr int V      = 4096;   // vocab (K)
constexpr int D      = 32;     // embed dim (N)
constexpr int KV     = 64;     // v per chunk
constexpr int WM     = 8;      // rows per block
constexpr int KWAVES = 4;      // waves per block = K-split
constexpr int KQ     = V / KWAVES;     // 1024
constexpr int NCHUNK = KQ / KV;        // 16
constexpr int NBUF   = 4;              // LDS ring (depth-2 prefetch)

#define FMA4(A, S, W4) \
  do { (A).x = fmaf((S), (W4).x, (A).x); \
       (A).y = fmaf((S), (W4).y, (A).y); \
       (A).z = fmaf((S), (W4).z, (A).z); \
       (A).w = fmaf((S), (W4).w, (A).w); } while (0)

__global__ __launch_bounds__(KWAVES * 64, 4)
void WeightedEmbedding_48249662603573_kernel(const float* __restrict__ x,
                                             const float* __restrict__ w,
                                             float* __restrict__ out,
                                             int M) {
  __shared__ float xs[KWAVES][NBUF][WM][KV];   // 32 KB, wave-private slices
  __shared__ f32x4 red[KWAVES][WM][8];         // 4 KB

  const int tid  = threadIdx.x;
  const int kq   = tid >> 6;   // wave id = K-quarter (wave-uniform)
  const int lane = tid & 63;
  const int d4   = lane & 7;   // owns d = d4*4 .. +3
  const int h    = lane >> 3;  // v-phase: v = v0 + h*8 .. +7
  const int r0   = blockIdx.x * WM;
  const int k0   = kq * KQ;

  // Per-lane staging source: lane i covers row r0 + i/16, cols (i%16)*4..+3
  // of the chunk. Two 1KB instrs per chunk (rows 0-3, rows 4-7).
  const float* gsrc = x + (size_t)(r0 + (lane >> 4)) * V + k0 + (lane & 15) * 4;

  // STAGE chunk index cc (wraps; wrap overwrites a consumed buffer, harmless)
  #define STAGE(cc)                                                          \
    do {                                                                     \
      const int b_ = (cc) & (NBUF - 1);                                      \
      const float* s_ = gsrc + (size_t)(cc) * KV;                            \
      __builtin_amdgcn_global_load_lds(                                      \
          (const __attribute__((address_space(1))) void*)s_,                 \
          (__attribute__((address_space(3))) void*)&xs[kq][b_][0][0],        \
          16, 0, 0);                                                         \
      __builtin_amdgcn_global_load_lds(                                      \
          (const __attribute__((address_space(1))) void*)(s_ + 4 * (size_t)V), \
          (__attribute__((address_space(3))) void*)&xs[kq][b_][4][0],        \
          16, 0, 0);                                                         \
    } while (0)

  f32x4 acc[WM];
#pragma unroll
  for (int m = 0; m < WM; ++m) acc[m] = (f32x4)(0.f);

  const float* wbase = w + (size_t)(k0 + h * 8) * D + d4 * 4;

  // prologue: depth-2 prefetch
  STAGE(0);
  STAGE(1);

  for (int c = 0; c < NCHUNK; ++c) {
    // keep the pipeline full (wraps near the end; overwrites consumed bufs)
    STAGE((c + 2) & (NCHUNK - 1));

    // stage(c) provably retired once only the 4 younger stage ops may remain
    // (vmcnt retires in issue order). Prefetches stay in flight — never drain.
    asm volatile("s_waitcnt vmcnt(4)" ::: "memory");

    // W chunk -> registers (8 independent L2-hot loads)
    f32x4 wr[8];
    const float* wp = wbase + (size_t)(c * KV) * D;
#pragma unroll
    for (int j = 0; j < 8; ++j)
      wr[j] = *(const f32x4*)(wp + (size_t)j * D);

    const float* xp = &xs[kq][c & (NBUF - 1)][0][0];
#pragma unroll
    for (int m = 0; m < WM; ++m) {
      f32x4 xa = *(const f32x4*)(xp + m * KV + h * 8);
      f32x4 xb = *(const f32x4*)(xp + m * KV + h * 8 + 4);
      FMA4(acc[m], xa.x, wr[0]);
      FMA4(acc[m], xa.y, wr[1]);
      FMA4(acc[m], xa.z, wr[2]);
      FMA4(acc[m], xa.w, wr[3]);
      FMA4(acc[m], xb.x, wr[4]);
      FMA4(acc[m], xb.y, wr[5]);
      FMA4(acc[m], xb.z, wr[6]);
      FMA4(acc[m], xb.w, wr[7]);
    }
  }

  // --- butterfly reduce across the 8 v-phase lanes (lane bits 3..5)
#pragma unroll
  for (int off = 8; off <= 32; off <<= 1) {
#pragma unroll
    for (int m = 0; m < WM; ++m) {
      acc[m].x += __shfl_xor(acc[m].x, off, 64);
      acc[m].y += __shfl_xor(acc[m].y, off, 64);
      acc[m].z += __shfl_xor(acc[m].z, off, 64);
      acc[m].w += __shfl_xor(acc[m].w, off, 64);
    }
  }

  // lane (h,d4) holds row h's partial for this K-quarter (static pick, rule #20)
  f32x4 res = acc[0];
#pragma unroll
  for (int m = 1; m < WM; ++m)
    if (h == m) res = acc[m];

  // --- cross-wave (K-quarter) reduce through LDS
  red[kq][h][d4] = res;
  __syncthreads();

  const int row = tid >> 5;        // 0..7
  const int d   = tid & 31;        // 0..31
  const float* rf = (const float*)red;
  const int idx = row * D + d;     // within one kq slice (256 floats)
  float s = rf[idx] + rf[256 + idx] + rf[512 + idx] + rf[768 + idx];
  if (r0 + row < M)
    out[(size_t)(r0 + row) * D + d] = s;
}

extern "C" void kernel_launch(void* const* d_in, const int* in_sizes, int n_in,
                              void* d_out, int out_size, void* d_ws, size_t ws_size,
                              hipStream_t stream) {
  const float* x = (const float*)d_in[0];
  const float* w = (const float*)d_in[1];
  float* out = (float*)d_out;

  const int M = in_sizes[0] / V;           // 8192
  dim3 grid((M + WM - 1) / WM);            // 1024 blocks = 4 blocks/CU exactly
  dim3 block(KWAVES * 64);                 // 256 threads = 4 waves
  hipLaunchKernelGGL(WeightedEmbedding_48249662603573_kernel,
                     grid, block, 0, stream, x, w, out, M);
}

// Round 5
// 208.072 us; speedup vs baseline: 1.6153x; 1.0155x over previous
//
#include <hip/hip_runtime.h>

// WeightedEmbedding: out[b,s,d] = sum_v x[b,s,v] * W[v,d]
// GEMM M=B*S=8192, K=V=4096, N=D=32, fp32.
//
// Round-5: fix the vmcnt pipeline drain found in r4. Issue order per chunk:
//   W(c+1) regs [8 ops] -> STAGE(c+2) [2 ops] -> s_waitcnt vmcnt(12)
// 12 = ops younger than W(c) (S(c+1)=2 + W(c+1)=8 + S(c+2)=2), so the wait
// proves W(c) AND S(c) retired WITHOUT draining prefetches (in-order vmcnt
// retirement). W double-buffered in registers (wrA/wrB, x2-unrolled loop,
// static indexing per rule #20). x staged via async global_load_lds into a
// wave-private 4-buffer ring. No barriers in the main loop.

typedef float f32x4 __attribute__((ext_vector_type(4)));

constexpr int V      = 4096;   // vocab (K)
constexpr int D      = 32;     // embed dim (N)
constexpr int KV     = 64;     // v per chunk
constexpr int WM     = 8;      // rows per block
constexpr int KWAVES = 4;      // waves per block = K-split
constexpr int KQ     = V / KWAVES;     // 1024
constexpr int NCHUNK = KQ / KV;        // 16
constexpr int NBUF   = 4;              // LDS ring (depth-2 prefetch)

#define FMA4(A, S, W4) \
  do { (A).x = fmaf((S), (W4).x, (A).x); \
       (A).y = fmaf((S), (W4).y, (A).y); \
       (A).z = fmaf((S), (W4).z, (A).z); \
       (A).w = fmaf((S), (W4).w, (A).w); } while (0)

__global__ __launch_bounds__(KWAVES * 64, 4)
void WeightedEmbedding_48249662603573_kernel(const float* __restrict__ x,
                                             const float* __restrict__ w,
                                             float* __restrict__ out,
                                             int M) {
  __shared__ float xs[KWAVES][NBUF][WM][KV];   // 32 KB, wave-private slices
  __shared__ f32x4 red[KWAVES][WM][8];         // 4 KB

  const int tid  = threadIdx.x;
  const int kq   = tid >> 6;   // wave id = K-quarter (wave-uniform)
  const int lane = tid & 63;
  const int d4   = lane & 7;   // owns d = d4*4 .. +3
  const int h    = lane >> 3;  // v-phase: v = v0 + h*8 .. +7
  const int r0   = blockIdx.x * WM;
  const int k0   = kq * KQ;

  // Per-lane staging source: lane i covers row r0 + i/16, cols (i%16)*4..+3.
  const float* gsrc = x + (size_t)(r0 + (lane >> 4)) * V + k0 + (lane & 15) * 4;

  #define STAGE(cc)                                                            \
    do {                                                                       \
      const int b_ = (cc) & (NBUF - 1);                                        \
      const float* s_ = gsrc + (size_t)((cc) & (NCHUNK - 1)) * KV;             \
      __builtin_amdgcn_global_load_lds(                                        \
          (const __attribute__((address_space(1))) void*)s_,                   \
          (__attribute__((address_space(3))) void*)&xs[kq][b_][0][0],          \
          16, 0, 0);                                                           \
      __builtin_amdgcn_global_load_lds(                                        \
          (const __attribute__((address_space(1))) void*)(s_ + 4 * (size_t)V), \
          (__attribute__((address_space(3))) void*)&xs[kq][b_][4][0],          \
          16, 0, 0);                                                           \
    } while (0)

  const float* wbase = w + (size_t)(k0 + h * 8) * D + d4 * 4;

  // 8 independent strided f32x4 loads of W chunk cc into named array DST
  #define LOADW(DST, cc)                                                       \
    do {                                                                       \
      const float* wp_ = wbase + (size_t)(((cc) & (NCHUNK - 1)) * KV) * D;     \
      _Pragma("unroll")                                                        \
      for (int j = 0; j < 8; ++j)                                              \
        DST[j] = *(const f32x4*)(wp_ + (size_t)j * D);                         \
    } while (0)

  // wait: exactly 12 VMEM ops younger than W(c); proves W(c)+S(c) retired,
  // keeps S(c+1), W(c+1), S(c+2) in flight. sched_barrier per rule #18.
  #define WAIT12()                                           \
    do {                                                     \
      asm volatile("s_waitcnt vmcnt(12)" ::: "memory");      \
      __builtin_amdgcn_sched_barrier(0);                     \
    } while (0)

  #define COMPUTE(cc, WR)                                      \
    do {                                                       \
      const float* xp_ = &xs[kq][(cc) & (NBUF - 1)][0][0];     \
      _Pragma("unroll")                                        \
      for (int m = 0; m < WM; ++m) {                           \
        f32x4 xa = *(const f32x4*)(xp_ + m * KV + h * 8);      \
        f32x4 xb = *(const f32x4*)(xp_ + m * KV + h * 8 + 4);  \
        FMA4(acc[m], xa.x, WR[0]);                             \
        FMA4(acc[m], xa.y, WR[1]);                             \
        FMA4(acc[m], xa.z, WR[2]);                             \
        FMA4(acc[m], xa.w, WR[3]);                             \
        FMA4(acc[m], xb.x, WR[4]);                             \
        FMA4(acc[m], xb.y, WR[5]);                             \
        FMA4(acc[m], xb.z, WR[6]);                             \
        FMA4(acc[m], xb.w, WR[7]);                             \
      }                                                        \
    } while (0)

  f32x4 acc[WM];
#pragma unroll
  for (int m = 0; m < WM; ++m) acc[m] = (f32x4)(0.f);

  f32x4 wrA[8], wrB[8];

  // prologue: W(0) then S(0), S(1)  (queue: W0[8], S0[2], S1[2])
  LOADW(wrA, 0);
  STAGE(0);
  STAGE(1);

  for (int c = 0; c < NCHUNK; c += 2) {
    LOADW(wrB, c + 1);        // W(c+1)
    STAGE(c + 2);             // S(c+2)
    WAIT12();                 // W(c), S(c) retired; 12 in flight
    COMPUTE(c, wrA);

    LOADW(wrA, c + 2);        // W(c+2) (wraps harmlessly on last pair)
    STAGE(c + 3);             // S(c+3)
    WAIT12();                 // W(c+1), S(c+1) retired
    COMPUTE(c + 1, wrB);
  }

  // --- butterfly reduce across the 8 v-phase lanes (lane bits 3..5)
#pragma unroll
  for (int off = 8; off <= 32; off <<= 1) {
#pragma unroll
    for (int m = 0; m < WM; ++m) {
      acc[m].x += __shfl_xor(acc[m].x, off, 64);
      acc[m].y += __shfl_xor(acc[m].y, off, 64);
      acc[m].z += __shfl_xor(acc[m].z, off, 64);
      acc[m].w += __shfl_xor(acc[m].w, off, 64);
    }
  }

  // lane (h,d4) holds row h's partial for this K-quarter (static pick, rule #20)
  f32x4 res = acc[0];
#pragma unroll
  for (int m = 1; m < WM; ++m)
    if (h == m) res = acc[m];

  // --- cross-wave (K-quarter) reduce through LDS
  red[kq][h][d4] = res;
  __syncthreads();

  const int row = tid >> 5;        // 0..7
  const int d   = tid & 31;        // 0..31
  const float* rf = (const float*)red;
  const int idx = row * D + d;     // within one kq slice (256 floats)
  float s = rf[idx] + rf[256 + idx] + rf[512 + idx] + rf[768 + idx];
  if (r0 + row < M)
    out[(size_t)(r0 + row) * D + d] = s;
}

extern "C" void kernel_launch(void* const* d_in, const int* in_sizes, int n_in,
                              void* d_out, int out_size, void* d_ws, size_t ws_size,
                              hipStream_t stream) {
  const float* x = (const float*)d_in[0];
  const float* w = (const float*)d_in[1];
  float* out = (float*)d_out;

  const int M = in_sizes[0] / V;           // 8192
  dim3 grid((M + WM - 1) / WM);            // 1024 blocks = 4 blocks/CU
  dim3 block(KWAVES * 64);                 // 256 threads = 4 waves
  hipLaunchKernelGGL(WeightedEmbedding_48249662603573_kernel,
                     grid, block, 0, stream, x, w, out, M);
}